// Round 5
// baseline (206.720 us; speedup 1.0000x reference)
//
#include <hip/hip_runtime.h>
#include <hip/hip_bf16.h>
#include <math.h>

#define NN    50000
#define DEG   16
#define FIN   256
#define FOUT  128
#define EE    (NN * DEG)
#define ALPHA 0.2f

#define BM 64
#define BN 256
#define BK 32
#define KV 768   // virtual K: [xh|xl|xh] x [Wa;Wa;Wb]

#define NSL 8    // feature slices (one per XCD)
#define SLW 32   // f16 per node per slice: {16 hi cols | 16 lo cols}
#define NPW 10   // nodes per wave in slice kernels (1250 blocks * 4 waves * 10 = 50000)

typedef __hip_bfloat16 bf16;
typedef _Float16 f16;
typedef __attribute__((ext_vector_type(2))) _Float16 f16x2;
typedef __attribute__((ext_vector_type(8))) short short8;
typedef __attribute__((ext_vector_type(4))) float f32x4;

// ---------------------------------------------------------------------------
// Split x (fp32 [NN][256]) into xcat (bf16 [NN][512] = [xh | xl]).
// ---------------------------------------------------------------------------
__global__ __launch_bounds__(256) void split_x_kernel(
    const float* __restrict__ x, bf16* __restrict__ xcat)
{
    const int total = NN * FIN / 4;
    for (int idx = blockIdx.x * 256 + threadIdx.x; idx < total; idx += gridDim.x * 256) {
        const float4 v = ((const float4*)x)[idx];
        const int row = idx >> 6;
        const int c4  = (idx & 63) * 4;
        short4 sh, sl;
        const float f[4] = {v.x, v.y, v.z, v.w};
#pragma unroll
        for (int j = 0; j < 4; ++j) {
            const bf16 hi = __float2bfloat16(f[j]);
            const bf16 lo = __float2bfloat16(f[j] - __bfloat162float(hi));
            ((bf16*)&sh)[j] = hi;
            ((bf16*)&sl)[j] = lo;
        }
        *(short4*)&xcat[(size_t)row * 512 + c4]       = sh;
        *(short4*)&xcat[(size_t)row * 512 + 256 + c4] = sl;
    }
}

// ---------------------------------------------------------------------------
// Build WcatT bf16 [256][768]: [Wa | Wa | Wb] per n-row.
// ---------------------------------------------------------------------------
__global__ __launch_bounds__(256) void split_w_kernel(
    const float* __restrict__ Wh, const float* __restrict__ Wl,
    bf16* __restrict__ WcatT)
{
    const int k = blockIdx.x;
    const int n = threadIdx.x;
    const float w = (n < FOUT) ? Wh[(size_t)k * FOUT + n]
                               : Wl[(size_t)k * FOUT + (n - FOUT)];
    const bf16 hi = __float2bfloat16(w);
    const bf16 lo = __float2bfloat16(w - __bfloat162float(hi));
    WcatT[(size_t)n * KV + k]       = hi;
    WcatT[(size_t)n * KV + 256 + k] = hi;
    WcatT[(size_t)n * KV + 512 + k] = lo;
}

// ---------------------------------------------------------------------------
// MFMA GEMM: h = A'(50000x768) @ B'(768x256), written SLICE-MAJOR f16
// [NSL][NN][SLW], plus sd epilogue: per-row logit scalars computed from the
// fp32 accumulators (s = h_row . a_s, d = h_row . a_d for hi and lo).
// ---------------------------------------------------------------------------
__global__ __launch_bounds__(256) void gemm_mfma_kernel(
    const bf16* __restrict__ xcat, const bf16* __restrict__ WcatT,
    const float* __restrict__ a_high, const float* __restrict__ a_low,
    f16* __restrict__ h16, float* __restrict__ sd_s, float* __restrict__ sd_d)
{
    __shared__ bf16 As[BM * BK];   // 4096 B (reused as sred in epilogue)
    __shared__ bf16 Bs[BN * BK];

    const int t    = threadIdx.x;
    const int lane = t & 63;
    const int w    = t >> 6;
    const int r0   = blockIdx.x * BM;

    f32x4 acc[4][4] = {};

    const int arow = t >> 2;
    const int asl  = ((t & 3) - (arow >> 1)) & 3;
    const size_t abase = (size_t)min(r0 + arow, NN - 1) * 512 + asl * 8;

    int bro[4], bsl[4];
#pragma unroll
    for (int i = 0; i < 4; ++i) {
        const int idx = t + i * 256;
        bro[i] = idx >> 2;
        bsl[i] = ((idx & 3) - (bro[i] >> 1)) & 3;
    }

    const int lr = lane & 15, lg = lane >> 4;

    for (int s = 0; s < KV / BK; ++s) {
        const int kt = s * BK;
        const int kA = (kt < 512) ? kt : kt - 512;

        __builtin_amdgcn_global_load_lds(
            (const __attribute__((address_space(1))) void*)(xcat + abase + kA),
            (__attribute__((address_space(3))) void*)((char*)As + t * 16),
            16, 0, 0);
#pragma unroll
        for (int i = 0; i < 4; ++i) {
            __builtin_amdgcn_global_load_lds(
                (const __attribute__((address_space(1))) void*)
                    (WcatT + (size_t)bro[i] * KV + kt + bsl[i] * 8),
                (__attribute__((address_space(3))) void*)((char*)Bs + (t + i * 256) * 16),
                16, 0, 0);
        }

        __syncthreads();

        short8 af[4], bfr[4];
#pragma unroll
        for (int mi = 0; mi < 4; ++mi) {
            const int row  = mi * 16 + lr;
            const int slot = (lg + (row >> 1)) & 3;
            af[mi] = *(const short8*)((const char*)As + row * 64 + slot * 16);
        }
#pragma unroll
        for (int ni = 0; ni < 4; ++ni) {
            const int row  = w * 64 + ni * 16 + lr;
            const int slot = (lg + (row >> 1)) & 3;
            bfr[ni] = *(const short8*)((const char*)Bs + row * 64 + slot * 16);
        }
#pragma unroll
        for (int mi = 0; mi < 4; ++mi)
#pragma unroll
            for (int ni = 0; ni < 4; ++ni)
                acc[mi][ni] = __builtin_amdgcn_mfma_f32_16x16x32_bf16(
                    af[mi], bfr[ni], acc[mi][ni], 0, 0, 0);

        __syncthreads();   // also guarantees As is dead before sred reuse
    }

    // ---- h16 store, slice-major [NSL][NN][SLW] ----
    const int slc_base = (w < 2) ? w * 4 : (w - 2) * 4;
    const int off      = ((w < 2) ? 0 : 16) + lr;
#pragma unroll
    for (int mi = 0; mi < 4; ++mi) {
        const int rowb = r0 + mi * 16 + lg * 4;
#pragma unroll
        for (int r = 0; r < 4; ++r) {
            const int row = rowb + r;
            if (row >= NN) continue;
#pragma unroll
            for (int ni = 0; ni < 4; ++ni)
                h16[((size_t)(slc_base + ni) * NN + row) * SLW + off] =
                    (f16)acc[mi][ni][r];
        }
    }

    // ---- sd epilogue: logit scalars from fp32 acc ----
    // wave w owns cols [64w,64w+64) of the 256-wide output (hi = cols<128).
    const float* aa = (w < 2) ? a_high : a_low;
    const int cb = (w < 2) ? w * 64 : (w - 2) * 64;
    float as_[4], ad_[4];
#pragma unroll
    for (int ni = 0; ni < 4; ++ni) {
        as_[ni] = aa[cb + ni * 16 + lr];          // a_s segment
        ad_[ni] = aa[FOUT + cb + ni * 16 + lr];   // a_d segment
    }
    float* sred = (float*)As;   // 4 waves * 2 scalars * 64 rows = 2 KB
#pragma unroll
    for (int mi = 0; mi < 4; ++mi)
#pragma unroll
        for (int r = 0; r < 4; ++r) {
            float ps = 0.f, pd = 0.f;
#pragma unroll
            for (int ni = 0; ni < 4; ++ni) {
                ps += acc[mi][ni][r] * as_[ni];
                pd += acc[mi][ni][r] * ad_[ni];
            }
#pragma unroll
            for (int o = 1; o < 16; o <<= 1) {
                ps += __shfl_xor(ps, o);
                pd += __shfl_xor(pd, o);
            }
            if (lr == 0) {
                const int row = mi * 16 + lg * 4 + r;
                sred[(w * 2 + 0) * 64 + row] = ps;
                sred[(w * 2 + 1) * 64 + row] = pd;
            }
        }
    __syncthreads();
    if (t < 64) {
        const int row = r0 + t;
        if (row < NN) {
            const float s_hi = sred[0 * 64 + t] + sred[2 * 64 + t];
            const float d_hi = sred[1 * 64 + t] + sred[3 * 64 + t];
            const float s_lo = sred[4 * 64 + t] + sred[6 * 64 + t];
            const float d_lo = sred[5 * 64 + t] + sred[7 * 64 + t];
            ((float2*)sd_s)[row] = make_float2(s_hi, s_lo);
            ((float2*)sd_d)[row] = make_float2(d_hi, d_lo);
        }
    }
}

// ---------------------------------------------------------------------------
// Per-edge normalized clipped weights, packed with d: ewd[e] = {d, (wh|wl)}.
// w_norm = min(e,6)/(rowsum+1e-16) in [0,1]; rowsum over UNCLIPPED e.
// One wave per node: lanes 0-15 hi, 16-31 lo (32-63 mirror, harmless).
// ---------------------------------------------------------------------------
__global__ __launch_bounds__(256) void weight_kernel(
    const int* __restrict__ dst, const float* __restrict__ sd_s,
    const float* __restrict__ sd_d, uint2* __restrict__ ewd)
{
    const int wid  = (blockIdx.x * 256 + threadIdx.x) >> 6;
    const int lane = threadIdx.x & 63;
    if (wid >= NN) return;

    const int e    = lane & 15;
    const int d_my = dst[wid * DEG + e];
    const bool whi = (lane & 16) == 0;
    const float2 s2 = ((const float2*)sd_s)[wid];
    const float2 dd = ((const float2*)sd_d)[d_my];
    const float l   = whi ? (s2.x + dd.x) : (s2.y + dd.y);
    const float ev  = __expf(-(l >= 0.f ? l : ALPHA * l));

    float rs = ev;
    rs += __shfl_xor(rs, 1);
    rs += __shfl_xor(rs, 2);
    rs += __shfl_xor(rs, 4);
    rs += __shfl_xor(rs, 8);
    const float wn = fminf(ev, 6.f) / (rs + 1e-16f);
    const float wl = __shfl(wn, e + 16);   // lo weight for edge e

    if (lane < 16) {
        const f16 wh16 = (f16)wn, wl16 = (f16)wl;
        const unsigned a = *(const unsigned short*)&wh16;
        const unsigned b = *(const unsigned short*)&wl16;
        ewd[wid * DEG + e] = make_uint2((unsigned)d_my, a | (b << 16));
    }
}

// ---------------------------------------------------------------------------
// Phase B (slice version): hn[s][i][.] = 16*h[s][i][.] +/- sum_d h[s][d][.]
// slice = blockIdx & 7 -> XCD-affine: each XCD gathers only its 3.2 MB slice.
// Wave handles NPW nodes; 4 subgroups of 16 lanes process 4 edges at a time;
// lane l16 covers f16x2 at offset 2*l16 (l16<8 = hi cols +, l16>=8 = lo -).
// ---------------------------------------------------------------------------
__global__ __launch_bounds__(256) void hn_slice_kernel(
    const f16* __restrict__ h16, const int* __restrict__ dst,
    f16* __restrict__ hn16)
{
    const int sl    = blockIdx.x & 7;
    const int chunk = blockIdx.x >> 3;
    const int wv    = threadIdx.x >> 6;
    const int lane  = threadIdx.x & 63;
    const int g     = lane >> 4;
    const int l16   = lane & 15;
    const float sgn = (l16 < 8) ? 1.f : -1.f;
    const f16* hsl  = h16 + (size_t)sl * NN * SLW;
    f16* osl        = hn16 + (size_t)sl * NN * SLW;

    const int n0 = (chunk * 4 + wv) * NPW;
    for (int ii = 0; ii < NPW; ++ii) {
        const int node = n0 + ii;                 // exact coverage, no guard
        const int dmy  = dst[node * DEG + l16];
        const f16x2 own = *(const f16x2*)(hsl + (size_t)node * SLW + l16 * 2);
        float2 acc;
        acc.x = (g == 0) ? 16.f * (float)own[0] : 0.f;
        acc.y = (g == 0) ? 16.f * (float)own[1] : 0.f;
#pragma unroll
        for (int i = 0; i < 4; ++i) {
            const int d = __shfl(dmy, g * 4 + i);
            const f16x2 gv = *(const f16x2*)(hsl + (size_t)d * SLW + l16 * 2);
            acc.x += sgn * (float)gv[0];
            acc.y += sgn * (float)gv[1];
        }
        acc.x += __shfl_xor(acc.x, 16); acc.y += __shfl_xor(acc.y, 16);
        acc.x += __shfl_xor(acc.x, 32); acc.y += __shfl_xor(acc.y, 32);
        if (lane < 16) {
            f16x2 o; o[0] = (f16)acc.x; o[1] = (f16)acc.y;
            *(f16x2*)(osl + (size_t)node * SLW + l16 * 2) = o;
        }
    }
}

// ---------------------------------------------------------------------------
// Phase C (slice version): out[i][16sl..16sl+16) = elu6(0.5*(hp_hi + hp_lo)),
// hp = sum_e w_norm[e] * hn[s][d_e][.]. Weights+d from packed ewd (no exp,
// no dst, no sd here). Same XCD-affine slice scheme.
// ---------------------------------------------------------------------------
__global__ __launch_bounds__(256) void out_slice_kernel(
    const f16* __restrict__ hn16, const uint2* __restrict__ ewd,
    float* __restrict__ out)
{
    const int sl    = blockIdx.x & 7;
    const int chunk = blockIdx.x >> 3;
    const int wv    = threadIdx.x >> 6;
    const int lane  = threadIdx.x & 63;
    const int g     = lane >> 4;
    const int l16   = lane & 15;
    const f16* hsl  = hn16 + (size_t)sl * NN * SLW;

    const int n0 = (chunk * 4 + wv) * NPW;
    for (int ii = 0; ii < NPW; ++ii) {
        const int node = n0 + ii;
        const uint2 ew = ewd[node * DEG + l16];
        float2 acc = make_float2(0.f, 0.f);
#pragma unroll
        for (int i = 0; i < 4; ++i) {
            const int e  = g * 4 + i;
            const int d  = __shfl((int)ew.x, e);
            const unsigned wp = (unsigned)__shfl((int)ew.y, e);
            const unsigned short wb =
                (l16 < 8) ? (unsigned short)(wp & 0xffffu)
                          : (unsigned short)(wp >> 16);
            const float w = (float)(*(const f16*)&wb);
            const f16x2 gv = *(const f16x2*)(hsl + (size_t)d * SLW + l16 * 2);
            acc.x += w * (float)gv[0];
            acc.y += w * (float)gv[1];
        }
        acc.x += __shfl_xor(acc.x, 16); acc.y += __shfl_xor(acc.y, 16);
        acc.x += __shfl_xor(acc.x, 32); acc.y += __shfl_xor(acc.y, 32);

        // mix hi (lanes l16<8) with lo partner (l16+8), elu6, store 16 cols
        const float px = __shfl(acc.x, l16 + 8);   // all lanes active
        const float py = __shfl(acc.y, l16 + 8);
        float vx = 0.5f * (acc.x + px);
        float vy = 0.5f * (acc.y + py);
        vx = fminf(vx > 0.f ? vx : expm1f(vx), 6.f);
        vy = fminf(vy > 0.f ? vy : expm1f(vy), 6.f);
        if (lane < 8)
            ((float2*)(out + (size_t)node * FOUT + sl * 16))[lane] =
                make_float2(vx, vy);
    }
}

// ---------------------------------------------------------------------------
// Workspace layout (84.4 MB):
//   [0, 51.2e6)          xcat bf16 [NN][512] -- dead after GEMM; overlaid by:
//       [0, 25.6e6)        hn16 f16 [NSL][NN][SLW]
//   [51.2e6, 76.8e6)     h16  f16 [NSL][NN][SLW]
//   [76.8e6, 77.2e6)     WcatT bf16 [256][768]
//   [77.2e6, 77.6e6)     sd_s fp32 [NN][2]
//   [77.6e6, 78.0e6)     sd_d fp32 [NN][2]
//   [78.0e6, 84.4e6)     ewd  uint2 [EE]
// ---------------------------------------------------------------------------
extern "C" void kernel_launch(void* const* d_in, const int* in_sizes, int n_in,
                              void* d_out, int out_size, void* d_ws, size_t ws_size,
                              hipStream_t stream)
{
    const float* x      = (const float*)d_in[0];
    const int*   edge   = (const int*)d_in[1];
    const float* Wh     = (const float*)d_in[2];
    const float* Wl     = (const float*)d_in[3];
    const float* a_high = (const float*)d_in[4];
    const float* a_low  = (const float*)d_in[5];
    const int*   dstv   = edge + EE;

    char* ws = (char*)d_ws;
    bf16*  xcat  = (bf16*)ws;
    f16*   hn16  = (f16*)ws;                       // alias (after GEMM)
    f16*   h16   = (f16*)(ws + 51200000);
    bf16*  WcatT = (bf16*)(ws + 76800000);
    float* sd_s  = (float*)(ws + 77200000);
    float* sd_d  = (float*)(ws + 77600000);
    uint2* ewd   = (uint2*)(ws + 78000000);

    split_x_kernel<<<dim3(2048), dim3(256), 0, stream>>>(x, xcat);
    split_w_kernel<<<dim3(256), dim3(256), 0, stream>>>(Wh, Wl, WcatT);
    gemm_mfma_kernel<<<dim3((NN + BM - 1) / BM), dim3(256), 0, stream>>>(
        xcat, WcatT, a_high, a_low, h16, sd_s, sd_d);
    weight_kernel<<<dim3((NN + 3) / 4), dim3(256), 0, stream>>>(dstv, sd_s, sd_d, ewd);
    hn_slice_kernel<<<dim3(NSL * (NN / (4 * NPW))), dim3(256), 0, stream>>>(
        h16, dstv, hn16);
    out_slice_kernel<<<dim3(NSL * (NN / (4 * NPW))), dim3(256), 0, stream>>>(
        hn16, ewd, (float*)d_out);
}

// Round 6
// 201.158 us; speedup vs baseline: 1.0277x; 1.0277x over previous
//
#include <hip/hip_runtime.h>
#include <hip/hip_bf16.h>
#include <math.h>

#define NN    50000
#define DEG   16
#define FIN   256
#define FOUT  128
#define EE    (NN * DEG)
#define ALPHA 0.2f

#define BM 64
#define BN 256
#define BK 32
#define KV 768   // virtual K: [xh|xl|xh] x [Wa;Wa;Wb]

typedef __hip_bfloat16 bf16;
typedef _Float16 f16;
typedef __attribute__((ext_vector_type(8))) _Float16 f16x8;
typedef __attribute__((ext_vector_type(8))) short short8;
typedef __attribute__((ext_vector_type(4))) float f32x4;

// ---------------------------------------------------------------------------
// Split x (fp32 [NN][256]) into xcat (bf16 [NN][512] = [xh | xl]).
// ---------------------------------------------------------------------------
__global__ __launch_bounds__(256) void split_x_kernel(
    const float* __restrict__ x, bf16* __restrict__ xcat)
{
    const int total = NN * FIN / 4;
    for (int idx = blockIdx.x * 256 + threadIdx.x; idx < total; idx += gridDim.x * 256) {
        const float4 v = ((const float4*)x)[idx];
        const int row = idx >> 6;
        const int c4  = (idx & 63) * 4;
        short4 sh, sl;
        const float f[4] = {v.x, v.y, v.z, v.w};
#pragma unroll
        for (int j = 0; j < 4; ++j) {
            const bf16 hi = __float2bfloat16(f[j]);
            const bf16 lo = __float2bfloat16(f[j] - __bfloat162float(hi));
            ((bf16*)&sh)[j] = hi;
            ((bf16*)&sl)[j] = lo;
        }
        *(short4*)&xcat[(size_t)row * 512 + c4]       = sh;
        *(short4*)&xcat[(size_t)row * 512 + 256 + c4] = sl;
    }
}

// ---------------------------------------------------------------------------
// Build WcatT bf16 [256][768]: [Wa | Wa | Wb] per n-row.
// ---------------------------------------------------------------------------
__global__ __launch_bounds__(256) void split_w_kernel(
    const float* __restrict__ Wh, const float* __restrict__ Wl,
    bf16* __restrict__ WcatT)
{
    const int k = blockIdx.x;
    const int n = threadIdx.x;
    const float w = (n < FOUT) ? Wh[(size_t)k * FOUT + n]
                               : Wl[(size_t)k * FOUT + (n - FOUT)];
    const bf16 hi = __float2bfloat16(w);
    const bf16 lo = __float2bfloat16(w - __bfloat162float(hi));
    WcatT[(size_t)n * KV + k]       = hi;
    WcatT[(size_t)n * KV + 256 + k] = hi;
    WcatT[(size_t)n * KV + 512 + k] = lo;
}

// ---------------------------------------------------------------------------
// MFMA GEMM: h16[NN][256] = A'(50000x768) @ B'(768x256), f16 out, row-major.
// sd epilogue: per-row logit scalars from the fp32 accumulators.
// ---------------------------------------------------------------------------
__global__ __launch_bounds__(256) void gemm_mfma_kernel(
    const bf16* __restrict__ xcat, const bf16* __restrict__ WcatT,
    const float* __restrict__ a_high, const float* __restrict__ a_low,
    f16* __restrict__ h16, float* __restrict__ sd_s, float* __restrict__ sd_d)
{
    __shared__ bf16 As[BM * BK];   // 4096 B (reused as sred in epilogue)
    __shared__ bf16 Bs[BN * BK];

    const int t    = threadIdx.x;
    const int lane = t & 63;
    const int w    = t >> 6;
    const int r0   = blockIdx.x * BM;

    f32x4 acc[4][4] = {};

    const int arow = t >> 2;
    const int asl  = ((t & 3) - (arow >> 1)) & 3;
    const size_t abase = (size_t)min(r0 + arow, NN - 1) * 512 + asl * 8;

    int bro[4], bsl[4];
#pragma unroll
    for (int i = 0; i < 4; ++i) {
        const int idx = t + i * 256;
        bro[i] = idx >> 2;
        bsl[i] = ((idx & 3) - (bro[i] >> 1)) & 3;
    }

    const int lr = lane & 15, lg = lane >> 4;

    for (int s = 0; s < KV / BK; ++s) {
        const int kt = s * BK;
        const int kA = (kt < 512) ? kt : kt - 512;

        __builtin_amdgcn_global_load_lds(
            (const __attribute__((address_space(1))) void*)(xcat + abase + kA),
            (__attribute__((address_space(3))) void*)((char*)As + t * 16),
            16, 0, 0);
#pragma unroll
        for (int i = 0; i < 4; ++i) {
            __builtin_amdgcn_global_load_lds(
                (const __attribute__((address_space(1))) void*)
                    (WcatT + (size_t)bro[i] * KV + kt + bsl[i] * 8),
                (__attribute__((address_space(3))) void*)((char*)Bs + (t + i * 256) * 16),
                16, 0, 0);
        }

        __syncthreads();

        short8 af[4], bfr[4];
#pragma unroll
        for (int mi = 0; mi < 4; ++mi) {
            const int row  = mi * 16 + lr;
            const int slot = (lg + (row >> 1)) & 3;
            af[mi] = *(const short8*)((const char*)As + row * 64 + slot * 16);
        }
#pragma unroll
        for (int ni = 0; ni < 4; ++ni) {
            const int row  = w * 64 + ni * 16 + lr;
            const int slot = (lg + (row >> 1)) & 3;
            bfr[ni] = *(const short8*)((const char*)Bs + row * 64 + slot * 16);
        }
#pragma unroll
        for (int mi = 0; mi < 4; ++mi)
#pragma unroll
            for (int ni = 0; ni < 4; ++ni)
                acc[mi][ni] = __builtin_amdgcn_mfma_f32_16x16x32_bf16(
                    af[mi], bfr[ni], acc[mi][ni], 0, 0, 0);

        __syncthreads();   // also guarantees As is dead before sred reuse
    }

    // ---- h16 store, row-major [NN][256] ----
#pragma unroll
    for (int mi = 0; mi < 4; ++mi) {
        const int rowb = r0 + mi * 16 + lg * 4;
#pragma unroll
        for (int r = 0; r < 4; ++r) {
            const int row = rowb + r;
            if (row >= NN) continue;
#pragma unroll
            for (int ni = 0; ni < 4; ++ni)
                h16[(size_t)row * 256 + w * 64 + ni * 16 + lr] = (f16)acc[mi][ni][r];
        }
    }

    // ---- sd epilogue: logit scalars from fp32 acc ----
    const float* aa = (w < 2) ? a_high : a_low;
    const int cb = (w < 2) ? w * 64 : (w - 2) * 64;
    float as_[4], ad_[4];
#pragma unroll
    for (int ni = 0; ni < 4; ++ni) {
        as_[ni] = aa[cb + ni * 16 + lr];
        ad_[ni] = aa[FOUT + cb + ni * 16 + lr];
    }
    float* sred = (float*)As;   // 4 waves * 2 scalars * 64 rows = 2 KB
#pragma unroll
    for (int mi = 0; mi < 4; ++mi)
#pragma unroll
        for (int r = 0; r < 4; ++r) {
            float ps = 0.f, pd = 0.f;
#pragma unroll
            for (int ni = 0; ni < 4; ++ni) {
                ps += acc[mi][ni][r] * as_[ni];
                pd += acc[mi][ni][r] * ad_[ni];
            }
#pragma unroll
            for (int o = 1; o < 16; o <<= 1) {
                ps += __shfl_xor(ps, o);
                pd += __shfl_xor(pd, o);
            }
            if (lr == 0) {
                const int row = mi * 16 + lg * 4 + r;
                sred[(w * 2 + 0) * 64 + row] = ps;
                sred[(w * 2 + 1) * 64 + row] = pd;
            }
        }
    __syncthreads();
    if (t < 64) {
        const int row = r0 + t;
        if (row < NN) {
            const float s_hi = sred[0 * 64 + t] + sred[2 * 64 + t];
            const float d_hi = sred[1 * 64 + t] + sred[3 * 64 + t];
            const float s_lo = sred[4 * 64 + t] + sred[6 * 64 + t];
            const float d_lo = sred[5 * 64 + t] + sred[7 * 64 + t];
            ((float2*)sd_s)[row] = make_float2(s_hi, s_lo);
            ((float2*)sd_d)[row] = make_float2(d_hi, d_lo);
        }
    }
}

// ---------------------------------------------------------------------------
// Per-edge NORMALIZED clipped weights packed with d: ewd[e] = {d, wh|wl<<16}.
// w = min(e,6)/(rowsum+1e-16); rowsum over UNCLIPPED e. (matches reference)
// ---------------------------------------------------------------------------
__global__ __launch_bounds__(256) void weight_kernel(
    const int* __restrict__ dst, const float* __restrict__ sd_s,
    const float* __restrict__ sd_d, uint2* __restrict__ ewd)
{
    const int wid  = (blockIdx.x * 256 + threadIdx.x) >> 6;
    const int lane = threadIdx.x & 63;
    if (wid >= NN) return;

    const int e    = lane & 15;
    const int d_my = dst[wid * DEG + e];
    const bool whi = (lane & 16) == 0;
    const float2 s2 = ((const float2*)sd_s)[wid];
    const float2 dd = ((const float2*)sd_d)[d_my];
    const float l   = whi ? (s2.x + dd.x) : (s2.y + dd.y);
    const float ev  = __expf(-(l >= 0.f ? l : ALPHA * l));

    float rs = ev;
    rs += __shfl_xor(rs, 1);
    rs += __shfl_xor(rs, 2);
    rs += __shfl_xor(rs, 4);
    rs += __shfl_xor(rs, 8);
    const float wn = fminf(ev, 6.f) / (rs + 1e-16f);
    const float wl = __shfl(wn, e + 16);   // lo weight for edge e

    if (lane < 16) {
        const f16 wh16 = (f16)wn, wl16 = (f16)wl;
        const unsigned a = *(const unsigned short*)&wh16;
        const unsigned b = *(const unsigned short*)&wl16;
        ewd[wid * DEG + e] = make_uint2((unsigned)d_my, a | (b << 16));
    }
}

// ---------------------------------------------------------------------------
// Phase B (v3): hn[i] = [16*h_hi[i] + sum_d h_hi[d] | 16*h_lo[i] - sum_d h_lo[d]]
// One wave per node. lane = el*32 + c: el = edge-pair slot (2 edges at a time,
// 32 lanes each covering the full 512 B row as f16x8), c = 16B chunk index
// (c<16 = hi cols +, c>=16 = lo cols -). 8 unrolled iterations = 16 edges.
// ---------------------------------------------------------------------------
__global__ __launch_bounds__(256) void hn_kernel(
    const f16* __restrict__ h16, const int* __restrict__ dst,
    f16* __restrict__ hn16)
{
    const int wid  = (blockIdx.x * 256 + threadIdx.x) >> 6;
    const int lane = threadIdx.x & 63;
    if (wid >= NN) return;
    const int c  = lane & 31;
    const int el = lane >> 5;
    const float sgn = (c < 16) ? 1.f : -1.f;

    const int d_all = dst[wid * DEG + (lane & 15)];
    const f16x8 own = *(const f16x8*)(h16 + (size_t)wid * 256 + c * 8);

    float acc[8] = {0.f, 0.f, 0.f, 0.f, 0.f, 0.f, 0.f, 0.f};
#pragma unroll
    for (int it = 0; it < 8; ++it) {
        const int d = __shfl(d_all, it * 2 + el);
        const f16x8 g = *(const f16x8*)(h16 + (size_t)d * 256 + c * 8);
#pragma unroll
        for (int j = 0; j < 8; ++j) acc[j] = fmaf(sgn, (float)g[j], acc[j]);
    }
#pragma unroll
    for (int j = 0; j < 8; ++j) acc[j] += __shfl_xor(acc[j], 32);

    if (lane < 32) {
        f16x8 o;
#pragma unroll
        for (int j = 0; j < 8; ++j) o[j] = (f16)(fmaf(16.f, (float)own[j], acc[j]));
        *(f16x8*)(hn16 + (size_t)wid * 256 + c * 8) = o;
    }
}

// ---------------------------------------------------------------------------
// Phase C (v3): out[i] = elu6(0.5*(hp_hi + hp_lo)), hp = sum_e w_e*hn[d_e].
// Weights pre-normalized+clipped in ewd -> no exp/divide here. Same 2-edge x
// 32-lane structure; hi/lo mix via shfl_xor(16) before elu6.
// ---------------------------------------------------------------------------
__global__ __launch_bounds__(256) void out_kernel(
    const f16* __restrict__ hn16, const uint2* __restrict__ ewd,
    float* __restrict__ out)
{
    const int wid  = (blockIdx.x * 256 + threadIdx.x) >> 6;
    const int lane = threadIdx.x & 63;
    if (wid >= NN) return;
    const int c  = lane & 31;
    const int el = lane >> 5;

    const uint2 ew = ewd[wid * DEG + (lane & 15)];

    float acc[8] = {0.f, 0.f, 0.f, 0.f, 0.f, 0.f, 0.f, 0.f};
#pragma unroll
    for (int it = 0; it < 8; ++it) {
        const int e = it * 2 + el;
        const int      d  = __shfl((int)ew.x, e);
        const unsigned wp = (unsigned)__shfl((int)ew.y, e);
        const unsigned short wb = (c < 16) ? (unsigned short)(wp & 0xffffu)
                                           : (unsigned short)(wp >> 16);
        const float w = (float)(*(const f16*)&wb);
        const f16x8 g = *(const f16x8*)(hn16 + (size_t)d * 256 + c * 8);
#pragma unroll
        for (int j = 0; j < 8; ++j) acc[j] = fmaf(w, (float)g[j], acc[j]);
    }
#pragma unroll
    for (int j = 0; j < 8; ++j) acc[j] += __shfl_xor(acc[j], 32);

    // mix hi (c<16) with lo partner (c+16), elu6, store 8 f32 cols per lane
    float4 v0, v1;
#pragma unroll
    for (int j = 0; j < 8; ++j) {
        const float p = __shfl_xor(acc[j], 16);
        float v = 0.5f * (acc[j] + p);
        v = (v > 0.f) ? v : (__expf(v) - 1.f);
        v = fminf(v, 6.f);
        if (j < 4) ((float*)&v0)[j] = v; else ((float*)&v1)[j - 4] = v;
    }
    if (lane < 16) {
        *(float4*)(out + (size_t)wid * FOUT + c * 8)     = v0;
        *(float4*)(out + (size_t)wid * FOUT + c * 8 + 4) = v1;
    }
}

// ---------------------------------------------------------------------------
// Workspace layout (84.4 MB):
//   [0, 51.2e6)          xcat bf16 [NN][512] -- dead after GEMM; overlaid by:
//       [0, 25.6e6)        hn16 f16 [NN][256]
//   [51.2e6, 76.8e6)     h16  f16 [NN][256]
//   [76.8e6, 77.2e6)     WcatT bf16 [256][768]
//   [77.2e6, 77.6e6)     sd_s fp32 [NN][2]
//   [77.6e6, 78.0e6)     sd_d fp32 [NN][2]
//   [78.0e6, 84.4e6)     ewd  uint2 [EE]
// ---------------------------------------------------------------------------
extern "C" void kernel_launch(void* const* d_in, const int* in_sizes, int n_in,
                              void* d_out, int out_size, void* d_ws, size_t ws_size,
                              hipStream_t stream)
{
    const float* x      = (const float*)d_in[0];
    const int*   edge   = (const int*)d_in[1];
    const float* Wh     = (const float*)d_in[2];
    const float* Wl     = (const float*)d_in[3];
    const float* a_high = (const float*)d_in[4];
    const float* a_low  = (const float*)d_in[5];
    const int*   dstv   = edge + EE;

    char* ws = (char*)d_ws;
    bf16*  xcat  = (bf16*)ws;
    f16*   hn16  = (f16*)ws;                       // alias (after GEMM)
    f16*   h16   = (f16*)(ws + 51200000);
    bf16*  WcatT = (bf16*)(ws + 76800000);
    float* sd_s  = (float*)(ws + 77200000);
    float* sd_d  = (float*)(ws + 77600000);
    uint2* ewd   = (uint2*)(ws + 78000000);

    split_x_kernel<<<dim3(2048), dim3(256), 0, stream>>>(x, xcat);
    split_w_kernel<<<dim3(256), dim3(256), 0, stream>>>(Wh, Wl, WcatT);
    gemm_mfma_kernel<<<dim3((NN + BM - 1) / BM), dim3(256), 0, stream>>>(
        xcat, WcatT, a_high, a_low, h16, sd_s, sd_d);
    weight_kernel<<<dim3((NN + 3) / 4), dim3(256), 0, stream>>>(dstv, sd_s, sd_d, ewd);
    hn_kernel<<<dim3((NN + 3) / 4), dim3(256), 0, stream>>>(h16, dstv, hn16);
    out_kernel<<<dim3((NN + 3) / 4), dim3(256), 0, stream>>>(hn16, ewd, (float*)d_out);
}

// Round 7
// 174.721 us; speedup vs baseline: 1.1831x; 1.1513x over previous
//
#include <hip/hip_runtime.h>
#include <hip/hip_bf16.h>
#include <math.h>

#define NN    50000
#define DEG   16
#define FIN   256
#define FOUT  128
#define EE    (NN * DEG)
#define ALPHA 0.2f

#define BM 64
#define BN 256
#define BK 32
#define KV 768   // virtual K: [xh|xl|xh] x [Wa;Wa;Wb]

#define SLW 32   // f16 per node per slice: {16 hi cols | 16 lo cols}, 64 B

typedef __hip_bfloat16 bf16;
typedef _Float16 f16;
typedef __attribute__((ext_vector_type(8))) _Float16 f16x8;
typedef __attribute__((ext_vector_type(8))) short short8;
typedef __attribute__((ext_vector_type(4))) float f32x4;

// ---------------------------------------------------------------------------
// Split x (fp32 [NN][256]) into xcat (bf16 [NN][512] = [xh | xl]).
// ---------------------------------------------------------------------------
__global__ __launch_bounds__(256) void split_x_kernel(
    const float* __restrict__ x, bf16* __restrict__ xcat)
{
    const int total = NN * FIN / 4;
    for (int idx = blockIdx.x * 256 + threadIdx.x; idx < total; idx += gridDim.x * 256) {
        const float4 v = ((const float4*)x)[idx];
        const int row = idx >> 6;
        const int c4  = (idx & 63) * 4;
        short4 sh, sl;
        const float f[4] = {v.x, v.y, v.z, v.w};
#pragma unroll
        for (int j = 0; j < 4; ++j) {
            const bf16 hi = __float2bfloat16(f[j]);
            const bf16 lo = __float2bfloat16(f[j] - __bfloat162float(hi));
            ((bf16*)&sh)[j] = hi;
            ((bf16*)&sl)[j] = lo;
        }
        *(short4*)&xcat[(size_t)row * 512 + c4]       = sh;
        *(short4*)&xcat[(size_t)row * 512 + 256 + c4] = sl;
    }
}

// ---------------------------------------------------------------------------
// Build WcatT bf16 [256][768]: [Wa | Wa | Wb] per n-row.
// ---------------------------------------------------------------------------
__global__ __launch_bounds__(256) void split_w_kernel(
    const float* __restrict__ Wh, const float* __restrict__ Wl,
    bf16* __restrict__ WcatT)
{
    const int k = blockIdx.x;
    const int n = threadIdx.x;
    const float w = (n < FOUT) ? Wh[(size_t)k * FOUT + n]
                               : Wl[(size_t)k * FOUT + (n - FOUT)];
    const bf16 hi = __float2bfloat16(w);
    const bf16 lo = __float2bfloat16(w - __bfloat162float(hi));
    WcatT[(size_t)n * KV + k]       = hi;
    WcatT[(size_t)n * KV + 256 + k] = hi;
    WcatT[(size_t)n * KV + 512 + k] = lo;
}

// ---------------------------------------------------------------------------
// MFMA GEMM: h = A'(50000x768) @ B'(768x256), written SLICE-MAJOR f16
// [8][NN][SLW] (slice s = {hi cols [16s,16s+16) | lo cols [16s,16s+16)}),
// plus sd epilogue: per-row logit scalars from the fp32 accumulators.
// ---------------------------------------------------------------------------
__global__ __launch_bounds__(256) void gemm_mfma_kernel(
    const bf16* __restrict__ xcat, const bf16* __restrict__ WcatT,
    const float* __restrict__ a_high, const float* __restrict__ a_low,
    f16* __restrict__ h16, float* __restrict__ sd_s, float* __restrict__ sd_d)
{
    __shared__ bf16 As[BM * BK];   // 4096 B (reused as sred in epilogue)
    __shared__ bf16 Bs[BN * BK];

    const int t    = threadIdx.x;
    const int lane = t & 63;
    const int w    = t >> 6;
    const int r0   = blockIdx.x * BM;

    f32x4 acc[4][4] = {};

    const int arow = t >> 2;
    const int asl  = ((t & 3) - (arow >> 1)) & 3;
    const size_t abase = (size_t)min(r0 + arow, NN - 1) * 512 + asl * 8;

    int bro[4], bsl[4];
#pragma unroll
    for (int i = 0; i < 4; ++i) {
        const int idx = t + i * 256;
        bro[i] = idx >> 2;
        bsl[i] = ((idx & 3) - (bro[i] >> 1)) & 3;
    }

    const int lr = lane & 15, lg = lane >> 4;

    for (int s = 0; s < KV / BK; ++s) {
        const int kt = s * BK;
        const int kA = (kt < 512) ? kt : kt - 512;

        __builtin_amdgcn_global_load_lds(
            (const __attribute__((address_space(1))) void*)(xcat + abase + kA),
            (__attribute__((address_space(3))) void*)((char*)As + t * 16),
            16, 0, 0);
#pragma unroll
        for (int i = 0; i < 4; ++i) {
            __builtin_amdgcn_global_load_lds(
                (const __attribute__((address_space(1))) void*)
                    (WcatT + (size_t)bro[i] * KV + kt + bsl[i] * 8),
                (__attribute__((address_space(3))) void*)((char*)Bs + (t + i * 256) * 16),
                16, 0, 0);
        }

        __syncthreads();

        short8 af[4], bfr[4];
#pragma unroll
        for (int mi = 0; mi < 4; ++mi) {
            const int row  = mi * 16 + lr;
            const int slot = (lg + (row >> 1)) & 3;
            af[mi] = *(const short8*)((const char*)As + row * 64 + slot * 16);
        }
#pragma unroll
        for (int ni = 0; ni < 4; ++ni) {
            const int row  = w * 64 + ni * 16 + lr;
            const int slot = (lg + (row >> 1)) & 3;
            bfr[ni] = *(const short8*)((const char*)Bs + row * 64 + slot * 16);
        }
#pragma unroll
        for (int mi = 0; mi < 4; ++mi)
#pragma unroll
            for (int ni = 0; ni < 4; ++ni)
                acc[mi][ni] = __builtin_amdgcn_mfma_f32_16x16x32_bf16(
                    af[mi], bfr[ni], acc[mi][ni], 0, 0, 0);

        __syncthreads();   // also guarantees As is dead before sred reuse
    }

    // ---- h16 store, slice-major [8][NN][SLW] ----
    const int slc_base = (w < 2) ? w * 4 : (w - 2) * 4;
    const int off      = ((w < 2) ? 0 : 16) + lr;
#pragma unroll
    for (int mi = 0; mi < 4; ++mi) {
        const int rowb = r0 + mi * 16 + lg * 4;
#pragma unroll
        for (int r = 0; r < 4; ++r) {
            const int row = rowb + r;
            if (row >= NN) continue;
#pragma unroll
            for (int ni = 0; ni < 4; ++ni)
                h16[((size_t)(slc_base + ni) * NN + row) * SLW + off] =
                    (f16)acc[mi][ni][r];
        }
    }

    // ---- sd epilogue: logit scalars from fp32 acc ----
    const float* aa = (w < 2) ? a_high : a_low;
    const int cb = (w < 2) ? w * 64 : (w - 2) * 64;
    float as_[4], ad_[4];
#pragma unroll
    for (int ni = 0; ni < 4; ++ni) {
        as_[ni] = aa[cb + ni * 16 + lr];
        ad_[ni] = aa[FOUT + cb + ni * 16 + lr];
    }
    float* sred = (float*)As;   // 4 waves * 2 scalars * 64 rows = 2 KB
#pragma unroll
    for (int mi = 0; mi < 4; ++mi)
#pragma unroll
        for (int r = 0; r < 4; ++r) {
            float ps = 0.f, pd = 0.f;
#pragma unroll
            for (int ni = 0; ni < 4; ++ni) {
                ps += acc[mi][ni][r] * as_[ni];
                pd += acc[mi][ni][r] * ad_[ni];
            }
#pragma unroll
            for (int o = 1; o < 16; o <<= 1) {
                ps += __shfl_xor(ps, o);
                pd += __shfl_xor(pd, o);
            }
            if (lr == 0) {
                const int row = mi * 16 + lg * 4 + r;
                sred[(w * 2 + 0) * 64 + row] = ps;
                sred[(w * 2 + 1) * 64 + row] = pd;
            }
        }
    __syncthreads();
    if (t < 64) {
        const int row = r0 + t;
        if (row < NN) {
            const float s_hi = sred[0 * 64 + t] + sred[2 * 64 + t];
            const float d_hi = sred[1 * 64 + t] + sred[3 * 64 + t];
            const float s_lo = sred[4 * 64 + t] + sred[6 * 64 + t];
            const float d_lo = sred[5 * 64 + t] + sred[7 * 64 + t];
            ((float2*)sd_s)[row] = make_float2(s_hi, s_lo);
            ((float2*)sd_d)[row] = make_float2(d_hi, d_lo);
        }
    }
}

// ---------------------------------------------------------------------------
// Per-edge NORMALIZED clipped weights packed with d: ewd[e] = {d, wh|wl<<16}.
// w = min(e,6)/(rowsum+1e-16); rowsum over UNCLIPPED e. (matches reference)
// ---------------------------------------------------------------------------
__global__ __launch_bounds__(256) void weight_kernel(
    const int* __restrict__ dst, const float* __restrict__ sd_s,
    const float* __restrict__ sd_d, uint2* __restrict__ ewd)
{
    const int wid  = (blockIdx.x * 256 + threadIdx.x) >> 6;
    const int lane = threadIdx.x & 63;
    if (wid >= NN) return;

    const int e    = lane & 15;
    const int d_my = dst[wid * DEG + e];
    const bool whi = (lane & 16) == 0;
    const float2 s2 = ((const float2*)sd_s)[wid];
    const float2 dd = ((const float2*)sd_d)[d_my];
    const float l   = whi ? (s2.x + dd.x) : (s2.y + dd.y);
    const float ev  = __expf(-(l >= 0.f ? l : ALPHA * l));

    float rs = ev;
    rs += __shfl_xor(rs, 1);
    rs += __shfl_xor(rs, 2);
    rs += __shfl_xor(rs, 4);
    rs += __shfl_xor(rs, 8);
    const float wn = fminf(ev, 6.f) / (rs + 1e-16f);
    const float wl = __shfl(wn, e + 16);   // lo weight for edge e

    if (lane < 16) {
        const f16 wh16 = (f16)wn, wl16 = (f16)wl;
        const unsigned a = *(const unsigned short*)&wh16;
        const unsigned b = *(const unsigned short*)&wl16;
        ewd[wid * DEG + e] = make_uint2((unsigned)d_my, a | (b << 16));
    }
}

// ---------------------------------------------------------------------------
// Phase B (slice v2, serial-edge): hn[s][n] = 16*h[s][n] +/- sum_d h[s][d].
// slice = blockIdx&7 -> XCD-affine; per-XCD working set 3.2 MB (L2-resident).
// Wave = 16 nodes x 4 chunks; lane (k,c) walks its node's 16 edges serially:
// no cross-lane reduce, no shfl decode. Gather = 16 B/lane, 64 B/edge line.
// Grid 8*625, block 320 (5 waves): 625*5*16 = 50000 exact, no guards.
// ---------------------------------------------------------------------------
__global__ __launch_bounds__(320) void hn_slice_kernel(
    const f16* __restrict__ h16, const int* __restrict__ dst,
    f16* __restrict__ hn16)
{
    const int sl    = blockIdx.x & 7;
    const int chunk = blockIdx.x >> 3;
    const int wv    = threadIdx.x >> 6;
    const int lane  = threadIdx.x & 63;
    const int k     = lane >> 2;
    const int c     = lane & 3;
    const int n     = (chunk * 5 + wv) * 16 + k;

    const char* hsl = (const char*)(h16 + (size_t)sl * NN * SLW);
    const float sgn = (c < 2) ? 1.f : -1.f;
    const unsigned coff = (unsigned)c * 16u;
    const unsigned noff = (unsigned)n * 64u + coff;

    const int* db = dst + n * DEG;
    const f16x8 own = *(const f16x8*)(hsl + noff);

    float acc[8] = {};
#pragma unroll
    for (int t = 0; t < DEG; ++t) {
        const unsigned d = (unsigned)db[t];
        const f16x8 g = *(const f16x8*)(hsl + (d * 64u + coff));
#pragma unroll
        for (int j = 0; j < 8; ++j) acc[j] = fmaf(sgn, (float)g[j], acc[j]);
    }
    f16x8 o;
#pragma unroll
    for (int j = 0; j < 8; ++j) o[j] = (f16)fmaf((float)own[j], 16.f, acc[j]);
    *(f16x8*)((char*)(hn16 + (size_t)sl * NN * SLW) + noff) = o;
}

// ---------------------------------------------------------------------------
// Phase C (slice v2, serial-edge): out[n][16sl..16sl+16) from hn slices.
// Per edge: 1 ewd record load (imm-offset folded), 1 select+cvt for w,
// 1 gather 16 B, 8 fma_mix. hi/lo mix via shfl_xor(2), elu6, 32 B store.
// ---------------------------------------------------------------------------
__global__ __launch_bounds__(320) void out_slice_kernel(
    const f16* __restrict__ hn16, const uint2* __restrict__ ewd,
    float* __restrict__ out)
{
    const int sl    = blockIdx.x & 7;
    const int chunk = blockIdx.x >> 3;
    const int wv    = threadIdx.x >> 6;
    const int lane  = threadIdx.x & 63;
    const int k     = lane >> 2;
    const int c     = lane & 3;
    const int n     = (chunk * 5 + wv) * 16 + k;
    const bool chi  = (c < 2);

    const char* hsl = (const char*)(hn16 + (size_t)sl * NN * SLW);
    const unsigned coff = (unsigned)c * 16u;
    const uint2* eb = ewd + n * DEG;

    float acc[8] = {};
#pragma unroll
    for (int t = 0; t < DEG; ++t) {
        const uint2 rec = eb[t];
        const unsigned short wu = chi ? (unsigned short)(rec.y & 0xffffu)
                                      : (unsigned short)(rec.y >> 16);
        const float w = (float)(*(const f16*)&wu);
        const f16x8 g = *(const f16x8*)(hsl + (rec.x * 64u + coff));
#pragma unroll
        for (int j = 0; j < 8; ++j) acc[j] = fmaf(w, (float)g[j], acc[j]);
    }

    float4 v0, v1;
#pragma unroll
    for (int j = 0; j < 8; ++j) {
        const float p = __shfl_xor(acc[j], 2);   // pair hi chunk c with lo chunk c^2
        float v = 0.5f * (acc[j] + p);
        v = (v > 0.f) ? v : (__expf(v) - 1.f);
        v = fminf(v, 6.f);
        if (j < 4) ((float*)&v0)[j] = v; else ((float*)&v1)[j - 4] = v;
    }
    if (chi) {
        float* op = out + (size_t)n * FOUT + sl * 16 + c * 8;
        *(float4*)op       = v0;
        *(float4*)(op + 4) = v1;
    }
}

// ---------------------------------------------------------------------------
// Workspace layout (84.4 MB):
//   [0, 51.2e6)          xcat bf16 [NN][512] -- dead after GEMM; overlaid by:
//       [0, 25.6e6)        hn16 f16 [8][NN][SLW]
//   [51.2e6, 76.8e6)     h16  f16 [8][NN][SLW]
//   [76.8e6, 77.2e6)     WcatT bf16 [256][768]
//   [77.2e6, 77.6e6)     sd_s fp32 [NN][2]
//   [77.6e6, 78.0e6)     sd_d fp32 [NN][2]
//   [78.0e6, 84.4e6)     ewd  uint2 [EE]
// ---------------------------------------------------------------------------
extern "C" void kernel_launch(void* const* d_in, const int* in_sizes, int n_in,
                              void* d_out, int out_size, void* d_ws, size_t ws_size,
                              hipStream_t stream)
{
    const float* x      = (const float*)d_in[0];
    const int*   edge   = (const int*)d_in[1];
    const float* Wh     = (const float*)d_in[2];
    const float* Wl     = (const float*)d_in[3];
    const float* a_high = (const float*)d_in[4];
    const float* a_low  = (const float*)d_in[5];
    const int*   dstv   = edge + EE;

    char* ws = (char*)d_ws;
    bf16*  xcat  = (bf16*)ws;
    f16*   hn16  = (f16*)ws;                       // alias (after GEMM)
    f16*   h16   = (f16*)(ws + 51200000);
    bf16*  WcatT = (bf16*)(ws + 76800000);
    float* sd_s  = (float*)(ws + 77200000);
    float* sd_d  = (float*)(ws + 77600000);
    uint2* ewd   = (uint2*)(ws + 78000000);

    split_x_kernel<<<dim3(2048), dim3(256), 0, stream>>>(x, xcat);
    split_w_kernel<<<dim3(256), dim3(256), 0, stream>>>(Wh, Wl, WcatT);
    gemm_mfma_kernel<<<dim3((NN + BM - 1) / BM), dim3(256), 0, stream>>>(
        xcat, WcatT, a_high, a_low, h16, sd_s, sd_d);
    weight_kernel<<<dim3((NN + 3) / 4), dim3(256), 0, stream>>>(dstv, sd_s, sd_d, ewd);
    hn_slice_kernel<<<dim3(8 * 625), dim3(320), 0, stream>>>(h16, dstv, hn16);
    out_slice_kernel<<<dim3(8 * 625), dim3(320), 0, stream>>>(hn16, ewd, (float*)d_out);
}

// Round 8
// 139.289 us; speedup vs baseline: 1.4841x; 1.2544x over previous
//
#include <hip/hip_runtime.h>
#include <hip/hip_bf16.h>
#include <math.h>

#define NN    50000
#define DEG   16
#define FIN   256
#define FOUT  128
#define EE    (NN * DEG)
#define ALPHA 0.2f

#define BM 64
#define BN 256

#define SLW 32   // f16 per node per slice: {16 hi cols | 16 lo cols}, 64 B

typedef __hip_bfloat16 bf16;
typedef _Float16 f16;
typedef __attribute__((ext_vector_type(8))) _Float16 f16x8;
typedef __attribute__((ext_vector_type(8))) short short8;
typedef __attribute__((ext_vector_type(4))) float f32x4;

// ---------------------------------------------------------------------------
// Build Wcat2 bf16 [256 n][512]: per n-row [Wa (256 k) | Wb (256 k)], where
// W[k][n] = (n<128 ? W_high : W_low), Wa = bf16-hi(W), Wb = bf16-lo(W).
// ---------------------------------------------------------------------------
__global__ __launch_bounds__(256) void split_w_kernel(
    const float* __restrict__ Wh, const float* __restrict__ Wl,
    bf16* __restrict__ Wcat2)
{
    const int k = blockIdx.x;    // 0..255
    const int n = threadIdx.x;   // 0..255
    const float w = (n < FOUT) ? Wh[(size_t)k * FOUT + n]
                               : Wl[(size_t)k * FOUT + (n - FOUT)];
    const bf16 hi = __float2bfloat16(w);
    const bf16 lo = __float2bfloat16(w - __bfloat162float(hi));
    Wcat2[(size_t)n * 512 + k]       = hi;
    Wcat2[(size_t)n * 512 + 256 + k] = lo;
}

// ---------------------------------------------------------------------------
// MFMA GEMM over PHYSICAL K (8 steps x 32 cols), A read directly from x fp32
// and split to bf16 hi/lo in-register (Ootomo bf16x3: acc = xh@Wa + xh@Wb
// + xl@Wa). 48 MFMA per wave per barrier (3x the old virtual-K structure).
// Output h16 slice-major [8][NN][SLW] + sd epilogue from fp32 accumulators.
// ---------------------------------------------------------------------------
__global__ __launch_bounds__(256) void gemm_mfma_kernel(
    const float* __restrict__ x, const bf16* __restrict__ Wcat2,
    const float* __restrict__ a_high, const float* __restrict__ a_low,
    f16* __restrict__ h16, float* __restrict__ sd_s, float* __restrict__ sd_d)
{
    __shared__ bf16 Ah[BM * 32];   // 4096 B (reused as sred in epilogue)
    __shared__ bf16 Al[BM * 32];   // 4096 B
    __shared__ bf16 Ba[BN * 32];   // 16384 B (Wa tile)
    __shared__ bf16 Bb[BN * 32];   // 16384 B (Wb tile)

    const int t    = threadIdx.x;
    const int lane = t & 63;
    const int w    = t >> 6;
    const int r0   = blockIdx.x * BM;

    f32x4 acc[4][4] = {};   // [mi][ni]

    // A staging: thread t owns x[r0 + (t>>2)][(t&3)*8 .. +8] of each 32-col step
    const int arow = t >> 2;
    const float* xsrc = x + (size_t)min(r0 + arow, NN - 1) * FIN + (t & 3) * 8;
    // LDS write addr: logical slot (t&3) goes to phys slot ((t&3)+(row>>1))&3
    const int awaddr = arow * 64 + ((((t & 3)) + (arow >> 1)) & 3) * 16;

    // B staging: 4 16-B chunks per thread per tile, inverse-swizzled source
    int bro[4], bsl[4];
#pragma unroll
    for (int i = 0; i < 4; ++i) {
        const int idx = t + i * 256;
        bro[i] = idx >> 2;
        bsl[i] = ((idx & 3) - (bro[i] >> 1)) & 3;
    }

    const int lr = lane & 15, lg = lane >> 4;

    float4 xa = *(const float4*)(xsrc + 0);
    float4 xb = *(const float4*)(xsrc + 4);

#pragma unroll
    for (int s = 0; s < 8; ++s) {
        const int c0 = s * 32;
        __syncthreads();   // previous step's LDS reads done; buffers free

        // ---- stage B tiles (Wa, Wb) via global_load_lds width-16 ----
#pragma unroll
        for (int i = 0; i < 4; ++i) {
            __builtin_amdgcn_global_load_lds(
                (const __attribute__((address_space(1))) void*)
                    (Wcat2 + (size_t)bro[i] * 512 + c0 + bsl[i] * 8),
                (__attribute__((address_space(3))) void*)((char*)Ba + (t + i * 256) * 16),
                16, 0, 0);
            __builtin_amdgcn_global_load_lds(
                (const __attribute__((address_space(1))) void*)
                    (Wcat2 + (size_t)bro[i] * 512 + 256 + c0 + bsl[i] * 8),
                (__attribute__((address_space(3))) void*)((char*)Bb + (t + i * 256) * 16),
                16, 0, 0);
        }

        // ---- stage A: split x (this step's regs) to bf16 hi/lo, ds_write ----
        {
            short8 hi8, lo8;
            const float f[8] = {xa.x, xa.y, xa.z, xa.w, xb.x, xb.y, xb.z, xb.w};
#pragma unroll
            for (int j = 0; j < 8; ++j) {
                const bf16 h = __float2bfloat16(f[j]);
                const bf16 l = __float2bfloat16(f[j] - __bfloat162float(h));
                ((bf16*)&hi8)[j] = h;
                ((bf16*)&lo8)[j] = l;
            }
            *(short8*)((char*)Ah + awaddr) = hi8;
            *(short8*)((char*)Al + awaddr) = lo8;
        }

        // ---- prefetch next step's x (drained by the barrier below) ----
        if (s < 7) {
            xa = *(const float4*)(xsrc + (s + 1) * 32 + 0);
            xb = *(const float4*)(xsrc + (s + 1) * 32 + 4);
        }

        __syncthreads();   // tiles ready

        // ---- 48 MFMA: xh@Wa, xh@Wb, xl@Wa ----
        short8 fh[4], wa[4], wb[4], fl[4];
#pragma unroll
        for (int mi = 0; mi < 4; ++mi) {
            const int row  = mi * 16 + lr;
            const int slot = (lg + (row >> 1)) & 3;
            fh[mi] = *(const short8*)((const char*)Ah + row * 64 + slot * 16);
        }
#pragma unroll
        for (int ni = 0; ni < 4; ++ni) {
            const int row  = w * 64 + ni * 16 + lr;
            const int slot = (lg + (row >> 1)) & 3;
            wa[ni] = *(const short8*)((const char*)Ba + row * 64 + slot * 16);
        }
#pragma unroll
        for (int mi = 0; mi < 4; ++mi)
#pragma unroll
            for (int ni = 0; ni < 4; ++ni)
                acc[mi][ni] = __builtin_amdgcn_mfma_f32_16x16x32_bf16(
                    fh[mi], wa[ni], acc[mi][ni], 0, 0, 0);
#pragma unroll
        for (int ni = 0; ni < 4; ++ni) {
            const int row  = w * 64 + ni * 16 + lr;
            const int slot = (lg + (row >> 1)) & 3;
            wb[ni] = *(const short8*)((const char*)Bb + row * 64 + slot * 16);
        }
#pragma unroll
        for (int mi = 0; mi < 4; ++mi)
#pragma unroll
            for (int ni = 0; ni < 4; ++ni)
                acc[mi][ni] = __builtin_amdgcn_mfma_f32_16x16x32_bf16(
                    fh[mi], wb[ni], acc[mi][ni], 0, 0, 0);
#pragma unroll
        for (int mi = 0; mi < 4; ++mi) {
            const int row  = mi * 16 + lr;
            const int slot = (lg + (row >> 1)) & 3;
            fl[mi] = *(const short8*)((const char*)Al + row * 64 + slot * 16);
        }
#pragma unroll
        for (int mi = 0; mi < 4; ++mi)
#pragma unroll
            for (int ni = 0; ni < 4; ++ni)
                acc[mi][ni] = __builtin_amdgcn_mfma_f32_16x16x32_bf16(
                    fl[mi], wa[ni], acc[mi][ni], 0, 0, 0);
    }

    // ---- h16 store, slice-major [8][NN][SLW] ----
    const int slc_base = (w < 2) ? w * 4 : (w - 2) * 4;
    const int off      = ((w < 2) ? 0 : 16) + lr;
#pragma unroll
    for (int mi = 0; mi < 4; ++mi) {
        const int rowb = r0 + mi * 16 + lg * 4;
#pragma unroll
        for (int r = 0; r < 4; ++r) {
            const int row = rowb + r;
            if (row >= NN) continue;
#pragma unroll
            for (int ni = 0; ni < 4; ++ni)
                h16[((size_t)(slc_base + ni) * NN + row) * SLW + off] =
                    (f16)acc[mi][ni][r];
        }
    }

    __syncthreads();   // all LDS frag reads done before Ah is reused as sred

    // ---- sd epilogue: logit scalars from fp32 acc ----
    const float* aa = (w < 2) ? a_high : a_low;
    const int cb = (w < 2) ? w * 64 : (w - 2) * 64;
    float as_[4], ad_[4];
#pragma unroll
    for (int ni = 0; ni < 4; ++ni) {
        as_[ni] = aa[cb + ni * 16 + lr];
        ad_[ni] = aa[FOUT + cb + ni * 16 + lr];
    }
    float* sred = (float*)Ah;   // 4 waves * 2 scalars * 64 rows = 2 KB
#pragma unroll
    for (int mi = 0; mi < 4; ++mi)
#pragma unroll
        for (int r = 0; r < 4; ++r) {
            float ps = 0.f, pd = 0.f;
#pragma unroll
            for (int ni = 0; ni < 4; ++ni) {
                ps += acc[mi][ni][r] * as_[ni];
                pd += acc[mi][ni][r] * ad_[ni];
            }
#pragma unroll
            for (int o = 1; o < 16; o <<= 1) {
                ps += __shfl_xor(ps, o);
                pd += __shfl_xor(pd, o);
            }
            if (lr == 0) {
                const int row = mi * 16 + lg * 4 + r;
                sred[(w * 2 + 0) * 64 + row] = ps;
                sred[(w * 2 + 1) * 64 + row] = pd;
            }
        }
    __syncthreads();
    if (t < 64) {
        const int row = r0 + t;
        if (row < NN) {
            const float s_hi = sred[0 * 64 + t] + sred[2 * 64 + t];
            const float d_hi = sred[1 * 64 + t] + sred[3 * 64 + t];
            const float s_lo = sred[4 * 64 + t] + sred[6 * 64 + t];
            const float d_lo = sred[5 * 64 + t] + sred[7 * 64 + t];
            ((float2*)sd_s)[row] = make_float2(s_hi, s_lo);
            ((float2*)sd_d)[row] = make_float2(d_hi, d_lo);
        }
    }
}

// ---------------------------------------------------------------------------
// Per-edge NORMALIZED clipped weights packed with d: ewd[e] = {d, wh|wl<<16}.
// w = min(e,6)/(rowsum+1e-16); rowsum over UNCLIPPED e. (matches reference)
// ---------------------------------------------------------------------------
__global__ __launch_bounds__(256) void weight_kernel(
    const int* __restrict__ dst, const float* __restrict__ sd_s,
    const float* __restrict__ sd_d, uint2* __restrict__ ewd)
{
    const int wid  = (blockIdx.x * 256 + threadIdx.x) >> 6;
    const int lane = threadIdx.x & 63;
    if (wid >= NN) return;

    const int e    = lane & 15;
    const int d_my = dst[wid * DEG + e];
    const bool whi = (lane & 16) == 0;
    const float2 s2 = ((const float2*)sd_s)[wid];
    const float2 dd = ((const float2*)sd_d)[d_my];
    const float l   = whi ? (s2.x + dd.x) : (s2.y + dd.y);
    const float ev  = __expf(-(l >= 0.f ? l : ALPHA * l));

    float rs = ev;
    rs += __shfl_xor(rs, 1);
    rs += __shfl_xor(rs, 2);
    rs += __shfl_xor(rs, 4);
    rs += __shfl_xor(rs, 8);
    const float wn = fminf(ev, 6.f) / (rs + 1e-16f);
    const float wl = __shfl(wn, e + 16);   // lo weight for edge e

    if (lane < 16) {
        const f16 wh16 = (f16)wn, wl16 = (f16)wl;
        const unsigned a = *(const unsigned short*)&wh16;
        const unsigned b = *(const unsigned short*)&wl16;
        ewd[wid * DEG + e] = make_uint2((unsigned)d_my, a | (b << 16));
    }
}

// ---------------------------------------------------------------------------
// Phase B (slice, serial-edge): hn[s][n] = 16*h[s][n] +/- sum_d h[s][d].
// slice = blockIdx&7 -> XCD-affine; per-XCD working set 3.2 MB (L2-resident).
// ---------------------------------------------------------------------------
__global__ __launch_bounds__(320) void hn_slice_kernel(
    const f16* __restrict__ h16, const int* __restrict__ dst,
    f16* __restrict__ hn16)
{
    const int sl    = blockIdx.x & 7;
    const int chunk = blockIdx.x >> 3;
    const int wv    = threadIdx.x >> 6;
    const int lane  = threadIdx.x & 63;
    const int k     = lane >> 2;
    const int c     = lane & 3;
    const int n     = (chunk * 5 + wv) * 16 + k;

    const char* hsl = (const char*)(h16 + (size_t)sl * NN * SLW);
    const float sgn = (c < 2) ? 1.f : -1.f;
    const unsigned coff = (unsigned)c * 16u;
    const unsigned noff = (unsigned)n * 64u + coff;

    const int* db = dst + n * DEG;
    const f16x8 own = *(const f16x8*)(hsl + noff);

    float acc[8] = {};
#pragma unroll
    for (int t = 0; t < DEG; ++t) {
        const unsigned d = (unsigned)db[t];
        const f16x8 g = *(const f16x8*)(hsl + (d * 64u + coff));
#pragma unroll
        for (int j = 0; j < 8; ++j) acc[j] = fmaf(sgn, (float)g[j], acc[j]);
    }
    f16x8 o;
#pragma unroll
    for (int j = 0; j < 8; ++j) o[j] = (f16)fmaf((float)own[j], 16.f, acc[j]);
    *(f16x8*)((char*)(hn16 + (size_t)sl * NN * SLW) + noff) = o;
}

// ---------------------------------------------------------------------------
// Phase C (slice, serial-edge): out[n][16sl..16sl+16) from hn slices.
// ---------------------------------------------------------------------------
__global__ __launch_bounds__(320) void out_slice_kernel(
    const f16* __restrict__ hn16, const uint2* __restrict__ ewd,
    float* __restrict__ out)
{
    const int sl    = blockIdx.x & 7;
    const int chunk = blockIdx.x >> 3;
    const int wv    = threadIdx.x >> 6;
    const int lane  = threadIdx.x & 63;
    const int k     = lane >> 2;
    const int c     = lane & 3;
    const int n     = (chunk * 5 + wv) * 16 + k;
    const bool chi  = (c < 2);

    const char* hsl = (const char*)(hn16 + (size_t)sl * NN * SLW);
    const unsigned coff = (unsigned)c * 16u;
    const uint2* eb = ewd + n * DEG;

    float acc[8] = {};
#pragma unroll
    for (int t = 0; t < DEG; ++t) {
        const uint2 rec = eb[t];
        const unsigned short wu = chi ? (unsigned short)(rec.y & 0xffffu)
                                      : (unsigned short)(rec.y >> 16);
        const float w = (float)(*(const f16*)&wu);
        const f16x8 g = *(const f16x8*)(hsl + (rec.x * 64u + coff));
#pragma unroll
        for (int j = 0; j < 8; ++j) acc[j] = fmaf(w, (float)g[j], acc[j]);
    }

    float4 v0, v1;
#pragma unroll
    for (int j = 0; j < 8; ++j) {
        const float p = __shfl_xor(acc[j], 2);   // pair hi chunk with lo chunk
        float v = 0.5f * (acc[j] + p);
        v = (v > 0.f) ? v : (__expf(v) - 1.f);
        v = fminf(v, 6.f);
        if (j < 4) ((float*)&v0)[j] = v; else ((float*)&v1)[j - 4] = v;
    }
    if (chi) {
        float* op = out + (size_t)n * FOUT + sl * 16 + c * 8;
        *(float4*)op       = v0;
        *(float4*)(op + 4) = v1;
    }
}

// ---------------------------------------------------------------------------
// Workspace layout (58.8 MB):
//   [0, 25.6e6)          h16  f16 [8][NN][SLW]
//   [25.6e6, 51.2e6)     hn16 f16 [8][NN][SLW]
//   [51.2e6, 51.46e6)    Wcat2 bf16 [256][512]
//   [51.6e6, 52.0e6)     sd_s fp32 [NN][2]
//   [52.0e6, 52.4e6)     sd_d fp32 [NN][2]
//   [52.4e6, 58.8e6)     ewd  uint2 [EE]
// ---------------------------------------------------------------------------
extern "C" void kernel_launch(void* const* d_in, const int* in_sizes, int n_in,
                              void* d_out, int out_size, void* d_ws, size_t ws_size,
                              hipStream_t stream)
{
    const float* x      = (const float*)d_in[0];
    const int*   edge   = (const int*)d_in[1];
    const float* Wh     = (const float*)d_in[2];
    const float* Wl     = (const float*)d_in[3];
    const float* a_high = (const float*)d_in[4];
    const float* a_low  = (const float*)d_in[5];
    const int*   dstv   = edge + EE;

    char* ws = (char*)d_ws;
    f16*   h16   = (f16*)ws;
    f16*   hn16  = (f16*)(ws + 25600000);
    bf16*  Wcat2 = (bf16*)(ws + 51200000);
    float* sd_s  = (float*)(ws + 51600000);
    float* sd_d  = (float*)(ws + 52000000);
    uint2* ewd   = (uint2*)(ws + 52400000);

    split_w_kernel<<<dim3(256), dim3(256), 0, stream>>>(Wh, Wl, Wcat2);
    gemm_mfma_kernel<<<dim3((NN + BM - 1) / BM), dim3(256), 0, stream>>>(
        x, Wcat2, a_high, a_low, h16, sd_s, sd_d);
    weight_kernel<<<dim3((NN + 3) / 4), dim3(256), 0, stream>>>(dstv, sd_s, sd_d, ewd);
    hn_slice_kernel<<<dim3(8 * 625), dim3(320), 0, stream>>>(h16, dstv, hn16);
    out_slice_kernel<<<dim3(8 * 625), dim3(320), 0, stream>>>(hn16, ewd, (float*)d_out);
}

// Round 9
// 130.346 us; speedup vs baseline: 1.5859x; 1.0686x over previous
//
#include <hip/hip_runtime.h>
#include <hip/hip_bf16.h>
#include <math.h>

#define NN    50000
#define DEG   16
#define FIN   256
#define FOUT  128
#define EE    (NN * DEG)
#define ALPHA 0.2f

#define BM 64
#define BN 256

#define SLW 32   // f16 per node per slice: {16 hi cols | 16 lo cols}, 64 B

typedef __hip_bfloat16 bf16;
typedef _Float16 f16;
typedef __attribute__((ext_vector_type(8))) _Float16 f16x8;
typedef __attribute__((ext_vector_type(8))) short short8;
typedef __attribute__((ext_vector_type(4))) float f32x4;
typedef __attribute__((ext_vector_type(8))) unsigned short u16x8;
typedef __attribute__((ext_vector_type(8))) unsigned int u32x8;

// ---------------------------------------------------------------------------
// Build Wcat2 bf16 [256 n][512]: per n-row [Wa (256 k) | Wb (256 k)], where
// W[k][n] = (n<128 ? W_high : W_low), Wa = bf16-hi(W), Wb = bf16-lo(W).
// ---------------------------------------------------------------------------
__global__ __launch_bounds__(256) void split_w_kernel(
    const float* __restrict__ Wh, const float* __restrict__ Wl,
    bf16* __restrict__ Wcat2)
{
    const int k = blockIdx.x;    // 0..255
    const int n = threadIdx.x;   // 0..255
    const float w = (n < FOUT) ? Wh[(size_t)k * FOUT + n]
                               : Wl[(size_t)k * FOUT + (n - FOUT)];
    const bf16 hi = __float2bfloat16(w);
    const bf16 lo = __float2bfloat16(w - __bfloat162float(hi));
    Wcat2[(size_t)n * 512 + k]       = hi;
    Wcat2[(size_t)n * 512 + 256 + k] = lo;
}

// ---------------------------------------------------------------------------
// MFMA GEMM, double-buffered single-barrier K-loop (8 steps x 32 cols).
// A read directly from x fp32, split to bf16 hi/lo in-register (Ootomo:
// acc = xh@Wa + xh@Wb + xl@Wa). 48 MFMA per wave per barrier; next-step
// tile loads overlap the MFMA phase. Output h16 slice-major [8][NN][SLW]
// + sd epilogue from fp32 accumulators.
// ---------------------------------------------------------------------------
__global__ __launch_bounds__(256) void gemm_mfma_kernel(
    const float* __restrict__ x, const bf16* __restrict__ Wcat2,
    const float* __restrict__ a_high, const float* __restrict__ a_low,
    f16* __restrict__ h16, float* __restrict__ sd_s, float* __restrict__ sd_d)
{
    __shared__ bf16 Ah[2][BM * 32];   // 2 x 4096 B ([0] reused as sred)
    __shared__ bf16 Al[2][BM * 32];
    __shared__ bf16 Ba[2][BN * 32];   // 2 x 16384 B (Wa)
    __shared__ bf16 Bb[2][BN * 32];   // 2 x 16384 B (Wb)

    const int t    = threadIdx.x;
    const int lane = t & 63;
    const int w    = t >> 6;
    const int r0   = blockIdx.x * BM;

    f32x4 acc[4][4] = {};   // [mi][ni]

    // A staging: thread t owns x[r0 + (t>>2)][(t&3)*8 .. +8] per 32-col step
    const int arow = t >> 2;
    const float* xsrc = x + (size_t)min(r0 + arow, NN - 1) * FIN + (t & 3) * 8;
    const int awaddr = arow * 64 + ((((t & 3)) + (arow >> 1)) & 3) * 16;

    // B staging: 4 16-B chunks per thread per tile, inverse-swizzled source
    int bro[4], bsl[4];
#pragma unroll
    for (int i = 0; i < 4; ++i) {
        const int idx = t + i * 256;
        bro[i] = idx >> 2;
        bsl[i] = ((idx & 3) - (bro[i] >> 1)) & 3;
    }

    const int lr = lane & 15, lg = lane >> 4;

    // ---- prologue: stage step 0, prefetch x(1) ----
    float4 xa = *(const float4*)(xsrc + 0);
    float4 xb = *(const float4*)(xsrc + 4);
#pragma unroll
    for (int i = 0; i < 4; ++i) {
        __builtin_amdgcn_global_load_lds(
            (const __attribute__((address_space(1))) void*)
                (Wcat2 + (size_t)bro[i] * 512 + 0 + bsl[i] * 8),
            (__attribute__((address_space(3))) void*)((char*)Ba[0] + (t + i * 256) * 16),
            16, 0, 0);
        __builtin_amdgcn_global_load_lds(
            (const __attribute__((address_space(1))) void*)
                (Wcat2 + (size_t)bro[i] * 512 + 256 + 0 + bsl[i] * 8),
            (__attribute__((address_space(3))) void*)((char*)Bb[0] + (t + i * 256) * 16),
            16, 0, 0);
    }
    {
        short8 hi8, lo8;
        const float f[8] = {xa.x, xa.y, xa.z, xa.w, xb.x, xb.y, xb.z, xb.w};
#pragma unroll
        for (int j = 0; j < 8; ++j) {
            const bf16 h = __float2bfloat16(f[j]);
            const bf16 l = __float2bfloat16(f[j] - __bfloat162float(h));
            ((bf16*)&hi8)[j] = h;
            ((bf16*)&lo8)[j] = l;
        }
        *(short8*)((char*)Ah[0] + awaddr) = hi8;
        *(short8*)((char*)Al[0] + awaddr) = lo8;
    }
    xa = *(const float4*)(xsrc + 32 + 0);   // x(1)
    xb = *(const float4*)(xsrc + 32 + 4);
    __syncthreads();   // step-0 tiles ready; x(1) landed

#pragma unroll
    for (int s = 0; s < 8; ++s) {
        const int cur = s & 1, nxt = cur ^ 1;

        if (s < 7) {
            // split x(s+1) (regs, arrived by prev barrier) -> A buf[nxt]
            short8 hi8, lo8;
            const float f[8] = {xa.x, xa.y, xa.z, xa.w, xb.x, xb.y, xb.z, xb.w};
#pragma unroll
            for (int j = 0; j < 8; ++j) {
                const bf16 h = __float2bfloat16(f[j]);
                const bf16 l = __float2bfloat16(f[j] - __bfloat162float(h));
                ((bf16*)&hi8)[j] = h;
                ((bf16*)&lo8)[j] = l;
            }
            *(short8*)((char*)Ah[nxt] + awaddr) = hi8;
            *(short8*)((char*)Al[nxt] + awaddr) = lo8;

            const int c1 = (s + 1) * 32;
#pragma unroll
            for (int i = 0; i < 4; ++i) {
                __builtin_amdgcn_global_load_lds(
                    (const __attribute__((address_space(1))) void*)
                        (Wcat2 + (size_t)bro[i] * 512 + c1 + bsl[i] * 8),
                    (__attribute__((address_space(3))) void*)((char*)Ba[nxt] + (t + i * 256) * 16),
                    16, 0, 0);
                __builtin_amdgcn_global_load_lds(
                    (const __attribute__((address_space(1))) void*)
                        (Wcat2 + (size_t)bro[i] * 512 + 256 + c1 + bsl[i] * 8),
                    (__attribute__((address_space(3))) void*)((char*)Bb[nxt] + (t + i * 256) * 16),
                    16, 0, 0);
            }
            if (s < 6) {
                xa = *(const float4*)(xsrc + (s + 2) * 32 + 0);
                xb = *(const float4*)(xsrc + (s + 2) * 32 + 4);
            }
        }

        // ---- 48 MFMA on buf[cur] ----
        short8 fh[4], wa[4], wb[4], fl[4];
#pragma unroll
        for (int mi = 0; mi < 4; ++mi) {
            const int row  = mi * 16 + lr;
            const int slot = (lg + (row >> 1)) & 3;
            fh[mi] = *(const short8*)((const char*)Ah[cur] + row * 64 + slot * 16);
        }
#pragma unroll
        for (int ni = 0; ni < 4; ++ni) {
            const int row  = w * 64 + ni * 16 + lr;
            const int slot = (lg + (row >> 1)) & 3;
            wa[ni] = *(const short8*)((const char*)Ba[cur] + row * 64 + slot * 16);
        }
#pragma unroll
        for (int mi = 0; mi < 4; ++mi)
#pragma unroll
            for (int ni = 0; ni < 4; ++ni)
                acc[mi][ni] = __builtin_amdgcn_mfma_f32_16x16x32_bf16(
                    fh[mi], wa[ni], acc[mi][ni], 0, 0, 0);
#pragma unroll
        for (int ni = 0; ni < 4; ++ni) {
            const int row  = w * 64 + ni * 16 + lr;
            const int slot = (lg + (row >> 1)) & 3;
            wb[ni] = *(const short8*)((const char*)Bb[cur] + row * 64 + slot * 16);
        }
#pragma unroll
        for (int mi = 0; mi < 4; ++mi)
#pragma unroll
            for (int ni = 0; ni < 4; ++ni)
                acc[mi][ni] = __builtin_amdgcn_mfma_f32_16x16x32_bf16(
                    fh[mi], wb[ni], acc[mi][ni], 0, 0, 0);
#pragma unroll
        for (int mi = 0; mi < 4; ++mi) {
            const int row  = mi * 16 + lr;
            const int slot = (lg + (row >> 1)) & 3;
            fl[mi] = *(const short8*)((const char*)Al[cur] + row * 64 + slot * 16);
        }
#pragma unroll
        for (int mi = 0; mi < 4; ++mi)
#pragma unroll
            for (int ni = 0; ni < 4; ++ni)
                acc[mi][ni] = __builtin_amdgcn_mfma_f32_16x16x32_bf16(
                    fl[mi], wa[ni], acc[mi][ni], 0, 0, 0);

        __syncthreads();   // next-step tiles ready; this step's reads done
    }

    // ---- h16 store, slice-major [8][NN][SLW] ----
    const int slc_base = (w < 2) ? w * 4 : (w - 2) * 4;
    const int off      = ((w < 2) ? 0 : 16) + lr;
#pragma unroll
    for (int mi = 0; mi < 4; ++mi) {
        const int rowb = r0 + mi * 16 + lg * 4;
#pragma unroll
        for (int r = 0; r < 4; ++r) {
            const int row = rowb + r;
            if (row >= NN) continue;
#pragma unroll
            for (int ni = 0; ni < 4; ++ni)
                h16[((size_t)(slc_base + ni) * NN + row) * SLW + off] =
                    (f16)acc[mi][ni][r];
        }
    }

    __syncthreads();   // LDS free before sred reuse

    // ---- sd epilogue: logit scalars from fp32 acc ----
    const float* aa = (w < 2) ? a_high : a_low;
    const int cb = (w < 2) ? w * 64 : (w - 2) * 64;
    float as_[4], ad_[4];
#pragma unroll
    for (int ni = 0; ni < 4; ++ni) {
        as_[ni] = aa[cb + ni * 16 + lr];
        ad_[ni] = aa[FOUT + cb + ni * 16 + lr];
    }
    float* sred = (float*)Ah[0];   // 4 waves * 2 scalars * 64 rows = 2 KB
#pragma unroll
    for (int mi = 0; mi < 4; ++mi)
#pragma unroll
        for (int r = 0; r < 4; ++r) {
            float ps = 0.f, pd = 0.f;
#pragma unroll
            for (int ni = 0; ni < 4; ++ni) {
                ps += acc[mi][ni][r] * as_[ni];
                pd += acc[mi][ni][r] * ad_[ni];
            }
#pragma unroll
            for (int o = 1; o < 16; o <<= 1) {
                ps += __shfl_xor(ps, o);
                pd += __shfl_xor(pd, o);
            }
            if (lr == 0) {
                const int row = mi * 16 + lg * 4 + r;
                sred[(w * 2 + 0) * 64 + row] = ps;
                sred[(w * 2 + 1) * 64 + row] = pd;
            }
        }
    __syncthreads();
    if (t < 64) {
        const int row = r0 + t;
        if (row < NN) {
            const float s_hi = sred[0 * 64 + t] + sred[2 * 64 + t];
            const float d_hi = sred[1 * 64 + t] + sred[3 * 64 + t];
            const float s_lo = sred[4 * 64 + t] + sred[6 * 64 + t];
            const float d_lo = sred[5 * 64 + t] + sred[7 * 64 + t];
            ((float2*)sd_s)[row] = make_float2(s_hi, s_lo);
            ((float2*)sd_d)[row] = make_float2(d_hi, d_lo);
        }
    }
}

// ---------------------------------------------------------------------------
// Per-edge weights, SoA: d16[e] = (u16)dst, w32[e] = fp16 wh | wl<<16.
// w = min(e,6)/(rowsum+1e-16); rowsum over UNCLIPPED e. (matches reference)
// ---------------------------------------------------------------------------
__global__ __launch_bounds__(256) void weight_kernel(
    const int* __restrict__ dst, const float* __restrict__ sd_s,
    const float* __restrict__ sd_d, unsigned short* __restrict__ d16,
    unsigned int* __restrict__ w32)
{
    const int wid  = (blockIdx.x * 256 + threadIdx.x) >> 6;
    const int lane = threadIdx.x & 63;
    if (wid >= NN) return;

    const int e    = lane & 15;
    const int d_my = dst[wid * DEG + e];
    const bool whi = (lane & 16) == 0;
    const float2 s2 = ((const float2*)sd_s)[wid];
    const float2 dd = ((const float2*)sd_d)[d_my];
    const float l   = whi ? (s2.x + dd.x) : (s2.y + dd.y);
    const float ev  = __expf(-(l >= 0.f ? l : ALPHA * l));

    float rs = ev;
    rs += __shfl_xor(rs, 1);
    rs += __shfl_xor(rs, 2);
    rs += __shfl_xor(rs, 4);
    rs += __shfl_xor(rs, 8);
    const float wn = fminf(ev, 6.f) / (rs + 1e-16f);
    const float wl = __shfl(wn, e + 16);   // lo weight for edge e

    if (lane < 16) {
        const f16 wh16 = (f16)wn, wl16 = (f16)wl;
        const unsigned a = *(const unsigned short*)&wh16;
        const unsigned b = *(const unsigned short*)&wl16;
        d16[wid * DEG + e] = (unsigned short)d_my;
        w32[wid * DEG + e] = a | (b << 16);
    }
}

// ---------------------------------------------------------------------------
// Phase B (slice v3, 2-half): hn[s][n] = 16*h[s][n] +/- sum_d h[s][d].
// slice = blockIdx&7 -> XCD-affine (3.2 MB slice, L2-resident).
// lane = k*8 + c*2 + hf: 8 nodes x 4 chunks x 2 edge-halves per wave.
// Each lane: 1 uint4 d16 load -> 8 independent 16 B gathers. Halves combine
// via shfl_xor(1). Block 320 = 5 waves = 40 nodes; grid 8 x 1250 exact.
// ---------------------------------------------------------------------------
__global__ __launch_bounds__(320) void hn_slice_kernel(
    const f16* __restrict__ h16, const unsigned short* __restrict__ d16,
    f16* __restrict__ hn16)
{
    const int sl    = blockIdx.x & 7;
    const int chunk = blockIdx.x >> 3;
    const int wv    = threadIdx.x >> 6;
    const int lane  = threadIdx.x & 63;
    const int k     = lane >> 3;
    const int c     = (lane >> 1) & 3;
    const int hf    = lane & 1;
    const int n     = (chunk * 5 + wv) * 8 + k;

    const char* hsl = (const char*)(h16 + (size_t)sl * NN * SLW);
    const float sgn = (c < 2) ? 1.f : -1.f;
    const unsigned coff = (unsigned)c * 16u;
    const unsigned noff = (unsigned)n * 64u + coff;

    const u16x8 d8 = *(const u16x8*)(d16 + n * DEG + hf * 8);
    const f16x8 own = *(const f16x8*)(hsl + noff);

    float acc[8] = {};
#pragma unroll
    for (int t = 0; t < 8; ++t) {
        const unsigned d = (unsigned)d8[t];
        const f16x8 g = *(const f16x8*)(hsl + (d * 64u + coff));
#pragma unroll
        for (int j = 0; j < 8; ++j) acc[j] = fmaf(sgn, (float)g[j], acc[j]);
    }
#pragma unroll
    for (int j = 0; j < 8; ++j) acc[j] += __shfl_xor(acc[j], 1);

    if (hf == 0) {
        f16x8 o;
#pragma unroll
        for (int j = 0; j < 8; ++j) o[j] = (f16)fmaf((float)own[j], 16.f, acc[j]);
        *(f16x8*)((char*)(hn16 + (size_t)sl * NN * SLW) + noff) = o;
    }
}

// ---------------------------------------------------------------------------
// Phase C (slice v3, 2-half): out[n][16sl..16sl+16) from hn slices.
// Per lane: uint4 d16 load + 2x uint4 w32 load + 8 gathers + 64 fma.
// Halves via shfl_xor(1), hi/lo mix via shfl_xor(4), elu6, 32 B store.
// ---------------------------------------------------------------------------
__global__ __launch_bounds__(320) void out_slice_kernel(
    const f16* __restrict__ hn16, const unsigned short* __restrict__ d16,
    const unsigned int* __restrict__ w32, float* __restrict__ out)
{
    const int sl    = blockIdx.x & 7;
    const int chunk = blockIdx.x >> 3;
    const int wv    = threadIdx.x >> 6;
    const int lane  = threadIdx.x & 63;
    const int k     = lane >> 3;
    const int c     = (lane >> 1) & 3;
    const int hf    = lane & 1;
    const int n     = (chunk * 5 + wv) * 8 + k;
    const bool chi  = (c < 2);

    const char* hsl = (const char*)(hn16 + (size_t)sl * NN * SLW);
    const unsigned coff = (unsigned)c * 16u;

    const u16x8 d8 = *(const u16x8*)(d16 + n * DEG + hf * 8);
    const u32x8 w8 = *(const u32x8*)(w32 + n * DEG + hf * 8);

    float acc[8] = {};
#pragma unroll
    for (int t = 0; t < 8; ++t) {
        const unsigned wp = w8[t];
        const unsigned short wu = chi ? (unsigned short)(wp & 0xffffu)
                                      : (unsigned short)(wp >> 16);
        const float w = (float)(*(const f16*)&wu);
        const f16x8 g = *(const f16x8*)(hsl + ((unsigned)d8[t] * 64u + coff));
#pragma unroll
        for (int j = 0; j < 8; ++j) acc[j] = fmaf(w, (float)g[j], acc[j]);
    }
#pragma unroll
    for (int j = 0; j < 8; ++j) acc[j] += __shfl_xor(acc[j], 1);

    float4 v0, v1;
#pragma unroll
    for (int j = 0; j < 8; ++j) {
        const float p = __shfl_xor(acc[j], 4);   // hi chunk c <-> lo chunk c^2
        float v = 0.5f * (acc[j] + p);
        v = (v > 0.f) ? v : (__expf(v) - 1.f);
        v = fminf(v, 6.f);
        if (j < 4) ((float*)&v0)[j] = v; else ((float*)&v1)[j - 4] = v;
    }
    if (chi && hf == 0) {
        float* op = out + (size_t)n * FOUT + sl * 16 + c * 8;
        *(float4*)op       = v0;
        *(float4*)(op + 4) = v1;
    }
}

// ---------------------------------------------------------------------------
// Workspace layout (~57.6 MB):
//   [0, 25.6e6)          h16  f16 [8][NN][SLW]
//   [25.6e6, 51.2e6)     hn16 f16 [8][NN][SLW]
//   [51.2e6, 51.73e6)    Wcat2 bf16 [256][512]
//   [51.8e6, 52.2e6)     sd_s fp32 [NN][2]
//   [52.2e6, 52.6e6)     sd_d fp32 [NN][2]
//   [52.6e6, 54.2e6)     d16  u16 [EE]
//   [54.4e6, 57.6e6)     w32  u32 [EE]
// ---------------------------------------------------------------------------
extern "C" void kernel_launch(void* const* d_in, const int* in_sizes, int n_in,
                              void* d_out, int out_size, void* d_ws, size_t ws_size,
                              hipStream_t stream)
{
    const float* x      = (const float*)d_in[0];
    const int*   edge   = (const int*)d_in[1];
    const float* Wh     = (const float*)d_in[2];
    const float* Wl     = (const float*)d_in[3];
    const float* a_high = (const float*)d_in[4];
    const float* a_low  = (const float*)d_in[5];
    const int*   dstv   = edge + EE;

    char* ws = (char*)d_ws;
    f16*   h16   = (f16*)ws;
    f16*   hn16  = (f16*)(ws + 25600000);
    bf16*  Wcat2 = (bf16*)(ws + 51200000);
    float* sd_s  = (float*)(ws + 51800000);
    float* sd_d  = (float*)(ws + 52200000);
    unsigned short* d16 = (unsigned short*)(ws + 52600000);
    unsigned int*   w32 = (unsigned int*)(ws + 54400000);

    split_w_kernel<<<dim3(256), dim3(256), 0, stream>>>(Wh, Wl, Wcat2);
    gemm_mfma_kernel<<<dim3((NN + BM - 1) / BM), dim3(256), 0, stream>>>(
        x, Wcat2, a_high, a_low, h16, sd_s, sd_d);
    weight_kernel<<<dim3((NN + 3) / 4), dim3(256), 0, stream>>>(dstv, sd_s, sd_d, d16, w32);
    hn_slice_kernel<<<dim3(8 * 1250), dim3(320), 0, stream>>>(h16, d16, hn16);
    out_slice_kernel<<<dim3(8 * 1250), dim3(320), 0, stream>>>(hn16, d16, w32, (float*)d_out);
}